// Round 2
// 8185.892 us; speedup vs baseline: 1.9838x; 1.9838x over previous
//
#include <hip/hip_runtime.h>

// Problem constants
#define TSTEPS 512
#define NBATCH 8
#define DDIM   512
#define UDIM   1024
#define VOUT   50257
#define VPAD   50304      // 393 * 128
#define MROWS  4096       // B*T
#define COOP_WGS 192

typedef _Float16 half8 __attribute__((ext_vector_type(8)));
typedef float    floatx4 __attribute__((ext_vector_type(4)));
typedef unsigned uintx4  __attribute__((ext_vector_type(4)));

__device__ __forceinline__ void gl2lds16(const void* g, void* l) {
  __builtin_amdgcn_global_load_lds(
      (const __attribute__((address_space(1))) unsigned int*)g,
      (__attribute__((address_space(3))) unsigned int*)l, 16, 0, 0);
}

// --- LLC-coherent (cross-XCD) memory helpers: sc0 sc1 bypasses L1+L2 ---------
__device__ __forceinline__ floatx4 llc_load_f4(const float* p) {
  floatx4 r;
  asm volatile("global_load_dwordx4 %0, %1, off sc0 sc1" : "=v"(r) : "v"(p));
  return r;
}
__device__ __forceinline__ void llc_store_f4(float* p, floatx4 v) {
  asm volatile("global_store_dwordx4 %0, %1, off sc0 sc1" :: "v"(p), "v"(v) : "memory");
}
__device__ __forceinline__ void llc_store_f1(float* p, float v) {
  asm volatile("global_store_dword %0, %1, off sc0 sc1" :: "v"(p), "v"(v) : "memory");
}
__device__ __forceinline__ void vm0_fence() {
  asm volatile("s_waitcnt vmcnt(0)" ::: "memory");
  __builtin_amdgcn_sched_barrier(0);
}
__device__ __forceinline__ unsigned llc_sum4(const unsigned* p) {
  uintx4 r;
  asm volatile("global_load_dwordx4 %0, %1, off sc0 sc1\n\ts_waitcnt vmcnt(0)"
               : "=v"(r) : "v"(p) : "memory");
  return r.x + r.y + r.z + r.w;
}
__device__ __forceinline__ void wait_sum(const unsigned* p, unsigned target) {
  while (llc_sum4(p) < target) __builtin_amdgcn_s_sleep(1);
}

// ---------------------------------------------------------------------------
// Convert x[4096,512] fp32 -> A1' = [Xh | Xh | Xl]  [4096,1536] fp16
// ---------------------------------------------------------------------------
__global__ void a1cvt_k(const float* __restrict__ x, _Float16* __restrict__ A1) {
  const int idx = blockIdx.x * 256 + threadIdx.x;   // < 4096*512
  const int m = idx >> 9, k = idx & 511;
  const float v = x[idx];
  const _Float16 h = (_Float16)v;
  const _Float16 l = (_Float16)(v - (float)h);
  const size_t base = (size_t)m * 1536;
  A1[base + k]        = h;
  A1[base + 512 + k]  = h;
  A1[base + 1024 + k] = l;
}

// ---------------------------------------------------------------------------
// Transpose+convert: src[K][Nsrc] fp32 -> dst[n][kofs + k] fp16 (hi or lo part)
// grid = (dst_rows/64, Ksrc/32). Rows n >= Nsrc get zeros (pads B for GEMM).
// ---------------------------------------------------------------------------
__global__ void transcvt_k(const float* __restrict__ src, _Float16* __restrict__ dst,
                           int Nsrc, int LDK, int kofs, int mode) {
  __shared__ _Float16 tl[32][72];
  const int n0 = blockIdx.x * 64, k0 = blockIdx.y * 32;
  const int tid = threadIdx.x;
  {
    const int n = tid & 63, kq = tid >> 6;   // kq 0..3
#pragma unroll
    for (int j = 0; j < 8; ++j) {
      const int k = kq * 8 + j;
      const float v = (n0 + n < Nsrc) ? src[(size_t)(k0 + k) * Nsrc + n0 + n] : 0.f;
      const _Float16 h = (_Float16)v;
      tl[k][n] = mode ? (_Float16)(v - (float)h) : h;
    }
  }
  __syncthreads();
  {
    const int nn = tid >> 2, kc = tid & 3;   // nn 0..63
    half8 pk;
#pragma unroll
    for (int j = 0; j < 8; ++j) pk[j] = tl[kc * 8 + j][nn];
    *(half8*)(dst + (size_t)(n0 + nn) * LDK + kofs + k0 + kc * 8) = pk;
  }
}

// ---------------------------------------------------------------------------
// fp16 MFMA GEMM: C[M,N] = A[M,K] * B[N,K]^T(+bias). 128x128 tile, BK=64.
// grid.x = (N/128)*32, decode mt = bx&31 (M=4096 always), nt = bx>>5.
// EPI=0: C = acc + bias (fp32).  EPI=1: C = exp(acc+bias), rowsums += partials.
// LDS: XOR-swizzled 16B chunks: slot(r,cs) holds global chunk cs^(r&7).
// ---------------------------------------------------------------------------
template <int EPI>
__global__ __launch_bounds__(256, 3)
void gemm_f16_k(const _Float16* __restrict__ A, const _Float16* __restrict__ B,
                const float* __restrict__ bias, float* __restrict__ C,
                float* __restrict__ rowsums, int K, int Nvalid, int ldc) {
  __shared__ _Float16 sA[128 * 64];
  __shared__ _Float16 sB[128 * 64];
  __shared__ float rsl[128];
  const int bx = blockIdx.x;
  const int mt = bx & 31, nt = bx >> 5;
  const int m0 = mt << 7, n0 = nt << 7;
  const int tid = threadIdx.x;
  const int lane = tid & 63;
  const int wv = __builtin_amdgcn_readfirstlane(tid >> 6);
  const int wm = wv & 1, wn = wv >> 1;

  floatx4 acc[4][4];
#pragma unroll
  for (int i = 0; i < 4; ++i)
#pragma unroll
    for (int j = 0; j < 4; ++j)
#pragma unroll
      for (int r = 0; r < 4; ++r) acc[i][j][r] = 0.f;

  const int kiters = K >> 6;
  for (int kk = 0; kk < kiters; ++kk) {
    const int k0 = kk << 6;
#pragma unroll
    for (int i = 0; i < 4; ++i) {
      const int s = (wv << 8) + (i << 6) + lane;
      const int r = s >> 3;
      const int cg = (s & 7) ^ (r & 7);
      gl2lds16(A + (size_t)(m0 + r) * K + (k0 + (cg << 3)),
               sA + (size_t)((wv << 8) + (i << 6)) * 8);
      gl2lds16(B + (size_t)(n0 + r) * K + (k0 + (cg << 3)),
               sB + (size_t)((wv << 8) + (i << 6)) * 8);
    }
    __syncthreads();
    const int q = lane >> 4, li = lane & 15;
#pragma unroll
    for (int s2 = 0; s2 < 2; ++s2) {
      half8 af[4], bf[4];
#pragma unroll
      for (int mi = 0; mi < 4; ++mi) {
        const int r = (wm << 6) + (mi << 4) + li;
        const int cg = (s2 << 2) + q;
        af[mi] = *(const half8*)(sA + (size_t)((r << 3) + (cg ^ (r & 7))) * 8);
      }
#pragma unroll
      for (int ni = 0; ni < 4; ++ni) {
        const int r = (wn << 6) + (ni << 4) + li;
        const int cg = (s2 << 2) + q;
        bf[ni] = *(const half8*)(sB + (size_t)((r << 3) + (cg ^ (r & 7))) * 8);
      }
#pragma unroll
      for (int mi = 0; mi < 4; ++mi)
#pragma unroll
        for (int ni = 0; ni < 4; ++ni)
          acc[mi][ni] = __builtin_amdgcn_mfma_f32_16x16x32_f16(af[mi], bf[ni], acc[mi][ni], 0, 0, 0);
    }
    __syncthreads();
  }

  if (EPI == 1 && tid < 128) rsl[tid] = 0.f;
  __syncthreads();

  const int q = lane >> 4, li = lane & 15;
#pragma unroll
  for (int ni = 0; ni < 4; ++ni) {
    const int n = n0 + (wn << 6) + (ni << 4) + li;
    const bool nv = (n < Nvalid);
    const float bv = nv ? bias[n] : 0.f;
#pragma unroll
    for (int mi = 0; mi < 4; ++mi) {
      const int mb = m0 + (wm << 6) + (mi << 4) + (q << 2);
      float vr[4];
#pragma unroll
      for (int r = 0; r < 4; ++r) {
        float v = acc[mi][ni][r] + bv;
        if (EPI == 1) v = __expf(v);
        if (nv) C[(size_t)(mb + r) * ldc + n] = v;
        vr[r] = nv ? v : 0.f;
      }
      if (EPI == 1) {
#pragma unroll
        for (int r = 0; r < 4; ++r) {
          vr[r] += __shfl_xor(vr[r], 1, 64);
          vr[r] += __shfl_xor(vr[r], 2, 64);
          vr[r] += __shfl_xor(vr[r], 4, 64);
          vr[r] += __shfl_xor(vr[r], 8, 64);
        }
        if (li == 0) {
          const int lrow = (wm << 6) + (mi << 4) + (q << 2);
#pragma unroll
          for (int r = 0; r < 4; ++r) atomicAdd(&rsl[lrow + r], vr[r]);
        }
      }
    }
  }
  if (EPI == 1) {
    __syncthreads();
    if (tid < 128) atomicAdd(&rowsums[m0 + tid], rsl[tid]);
  }
}

// ---------------------------------------------------------------------------
// Cooperative recurrence kernel, producer-consumer flag sync (no grid barrier).
// WG 0..63  : layer1, 16 cols each:  h1[t] = tanh(Xp1[t] + h1[t-1]@Wh1)
//             waits only on c1[t-1]==64 (its own 64-WG group) -> critical chain
// WG 64..191: layer2, 8 cols each:   h2[t] = tanh(h1[t]@Wx2 + h2[t-1]@Wh2 + b2)
//             waits on c1[t]==64 and c2[t-1]==128; trails with slack.
// H1/H2s slots are unique per t -> no WAR hazard -> no symmetric barrier needed.
// All cross-WG state moves via sc0 sc1 (LLC-coherent) loads/stores; no
// threadfence (no buffer_wbl2 / buffer_inv) anywhere -> Xp1/b2/weights stay
// cached in L1/L2 across iterations.
// Counters: c1[t][4], c2[t][4] split by (wg&3) to spread RMW serialization;
// consumers read each as one dwordx4 and sum.
// Thread map: tid = bg(1) | cg(2) | kg(5). k interleaved (k = kg*2 + 64j + {0,1}).
// Dynamic LDS: Wl[16*1024] | hbufA[8192] | hbufB[8192] | pbuf[128] floats.
// ---------------------------------------------------------------------------
__global__ __launch_bounds__(256)
void rnn_coop_k(const float* __restrict__ Xp1, const float* __restrict__ Wh1,
                const float* __restrict__ Wx2, const float* __restrict__ Wh2,
                const float* __restrict__ b2,
                float* __restrict__ H1, float* __restrict__ H2s,
                _Float16* __restrict__ H2f,
                unsigned* __restrict__ c1, unsigned* __restrict__ c2) {
  extern __shared__ float smem[];
  float* Wl    = smem;            // 16384 floats (64KB)
  float* hbufA = smem + 16384;    // 8192 floats (32KB)
  float* hbufB = smem + 24576;    // 8192 floats (32KB)
  float* pbuf  = smem + 32768;    // 128 floats

  const int wg = blockIdx.x;
  const bool isL1 = (wg < 64);
  const int tid = threadIdx.x;

  // Load weight slices into LDS (once, plain cached loads).
  if (isL1) {
    const int n0 = wg << 4;
    for (int idx = tid; idx < 16 * 1024; idx += 256) {
      const int k = idx >> 4, c = idx & 15;
      Wl[c * 1024 + k] = Wh1[(size_t)k * 1024 + n0 + c];
    }
  } else {
    const int n0 = (wg - 64) << 3;
    for (int idx = tid; idx < 8 * 1024; idx += 256) {
      const int k = idx >> 3, c = idx & 7;
      Wl[c * 1024 + k]       = Wx2[(size_t)k * 1024 + n0 + c];
      Wl[(8 + c) * 1024 + k] = Wh2[(size_t)k * 1024 + n0 + c];
    }
  }

  const int kg = tid & 31, cg = (tid >> 5) & 3, bg = tid >> 7;

  if (isL1) {
    // ---------------- layer 1: the serial critical chain ----------------
    const int n0c = (wg << 4) + (cg << 2);
    for (int t = 0; t < TSTEPS; ++t) {
      if (t > 0 && tid == 0) wait_sum(c1 + ((t - 1) << 2), 64);
      __syncthreads();  // flag observed by all; also covers Wl load at t=0

      if (t > 0) {
        const float* src = H1 + (size_t)(t - 1) * 8192;
        floatx4 tmp[8];
#pragma unroll
        for (int i = 0; i < 8; ++i) tmp[i] = llc_load_f4(src + ((tid + (i << 8)) << 2));
        vm0_fence();
#pragma unroll
        for (int i = 0; i < 8; ++i) ((floatx4*)hbufA)[tid + (i << 8)] = tmp[i];
      } else {
        const floatx4 z = {0.f, 0.f, 0.f, 0.f};
#pragma unroll
        for (int i = 0; i < 8; ++i) ((floatx4*)hbufA)[tid + (i << 8)] = z;
      }
      __syncthreads();

      float av[4][4];
#pragma unroll
      for (int b = 0; b < 4; ++b)
#pragma unroll
        for (int i = 0; i < 4; ++i) av[b][i] = 0.f;
#pragma unroll 4
      for (int j = 0; j < 16; ++j) {
        const int k0 = (kg << 1) + (j << 6);
        float2 hv[4], wvec[4];
#pragma unroll
        for (int b = 0; b < 4; ++b)
          hv[b] = *(const float2*)(hbufA + ((bg << 2) + b) * 1024 + k0);
#pragma unroll
        for (int i = 0; i < 4; ++i)
          wvec[i] = *(const float2*)(Wl + ((cg << 2) + i) * 1024 + k0);
#pragma unroll
        for (int b = 0; b < 4; ++b)
#pragma unroll
          for (int i = 0; i < 4; ++i)
            av[b][i] += hv[b].x * wvec[i].x + hv[b].y * wvec[i].y;
      }
#pragma unroll
      for (int b = 0; b < 4; ++b)
#pragma unroll
        for (int i = 0; i < 4; ++i) {
          float v = av[b][i];
          v += __shfl_xor(v, 1, 64);
          v += __shfl_xor(v, 2, 64);
          v += __shfl_xor(v, 4, 64);
          v += __shfl_xor(v, 8, 64);
          v += __shfl_xor(v, 16, 64);
          av[b][i] = v;
        }
      if (kg == 0) {
#pragma unroll
        for (int b = 0; b < 4; ++b) {
          const int bb = (bg << 2) + b;
          const float4 x4 = *(const float4*)(Xp1 + ((size_t)bb * TSTEPS + t) * 1024 + n0c);
          floatx4 h4;
          h4.x = tanhf(av[b][0] + x4.x);
          h4.y = tanhf(av[b][1] + x4.y);
          h4.z = tanhf(av[b][2] + x4.z);
          h4.w = tanhf(av[b][3] + x4.w);
          llc_store_f4(H1 + (size_t)t * 8192 + (size_t)bb * 1024 + n0c, h4);
        }
      }
      vm0_fence();      // this thread's sc1 stores acked at LLC
      __syncthreads();  // all threads' stores acked
      if (tid == 0)
        __hip_atomic_fetch_add(&c1[(t << 2) + (wg & 3)], 1u,
                               __ATOMIC_RELAXED, __HIP_MEMORY_SCOPE_AGENT);
    }
  } else {
    // ---------------- layer 2: trails layer 1 by one step ----------------
    const int n0 = (wg - 64) << 3;
    const float* hA_sel = (cg >= 2) ? hbufB : hbufA;
    for (int t = 0; t < TSTEPS; ++t) {
      if (tid == 0) {
        wait_sum(c1 + (t << 2), 64);
        if (t > 0) wait_sum(c2 + ((t - 1) << 2), 128);
      }
      __syncthreads();

      {
        const float* srcA = H1 + (size_t)t * 8192;
        floatx4 ta[8];
#pragma unroll
        for (int i = 0; i < 8; ++i) ta[i] = llc_load_f4(srcA + ((tid + (i << 8)) << 2));
        if (t > 0) {
          const float* srcB = H2s + (size_t)(t - 1) * 8192;
          floatx4 tb[8];
#pragma unroll
          for (int i = 0; i < 8; ++i) tb[i] = llc_load_f4(srcB + ((tid + (i << 8)) << 2));
          vm0_fence();
#pragma unroll
          for (int i = 0; i < 8; ++i) ((floatx4*)hbufA)[tid + (i << 8)] = ta[i];
#pragma unroll
          for (int i = 0; i < 8; ++i) ((floatx4*)hbufB)[tid + (i << 8)] = tb[i];
        } else {
          vm0_fence();
          const floatx4 z = {0.f, 0.f, 0.f, 0.f};
#pragma unroll
          for (int i = 0; i < 8; ++i) {
            ((floatx4*)hbufA)[tid + (i << 8)] = ta[i];
            ((floatx4*)hbufB)[tid + (i << 8)] = z;
          }
        }
      }
      __syncthreads();

      float av[4][4];
#pragma unroll
      for (int b = 0; b < 4; ++b)
#pragma unroll
        for (int i = 0; i < 4; ++i) av[b][i] = 0.f;
#pragma unroll 4
      for (int j = 0; j < 16; ++j) {
        const int k0 = (kg << 1) + (j << 6);
        float2 hv[4], wvec[4];
#pragma unroll
        for (int b = 0; b < 4; ++b)
          hv[b] = *(const float2*)(hA_sel + ((bg << 2) + b) * 1024 + k0);
#pragma unroll
        for (int i = 0; i < 4; ++i)
          wvec[i] = *(const float2*)(Wl + ((cg << 2) + i) * 1024 + k0);
#pragma unroll
        for (int b = 0; b < 4; ++b)
#pragma unroll
          for (int i = 0; i < 4; ++i)
            av[b][i] += hv[b].x * wvec[i].x + hv[b].y * wvec[i].y;
      }
#pragma unroll
      for (int b = 0; b < 4; ++b)
#pragma unroll
        for (int i = 0; i < 4; ++i) {
          float v = av[b][i];
          v += __shfl_xor(v, 1, 64);
          v += __shfl_xor(v, 2, 64);
          v += __shfl_xor(v, 4, 64);
          v += __shfl_xor(v, 8, 64);
          v += __shfl_xor(v, 16, 64);
          av[b][i] = v;
        }
      if (kg == 0) {
#pragma unroll
        for (int b = 0; b < 4; ++b)
#pragma unroll
          for (int i = 0; i < 4; ++i)
            pbuf[((cg << 2) + i) * 8 + (bg << 2) + b] = av[b][i];
      }
      __syncthreads();
      if (tid < 64) {
        const int c = tid & 7, b = tid >> 3;
        const int n = n0 + c;
        const float pre = pbuf[c * 8 + b] + pbuf[(c + 8) * 8 + b] + b2[n];
        const float h = tanhf(pre);
        llc_store_f1(H2s + (size_t)t * 8192 + (size_t)b * 1024 + n, h);
        H2f[((size_t)b * TSTEPS + t) * 1024 + n] = (_Float16)h;  // plain: post-kernel use
      }
      vm0_fence();
      __syncthreads();
      if (tid == 0)
        __hip_atomic_fetch_add(&c2[(t << 2) + (wg & 3)], 1u,
                               __ATOMIC_RELAXED, __HIP_MEMORY_SCOPE_AGENT);
    }
  }
}

// ---------------------------------------------------------------------------
// out[row, :] *= 1/rowsum[row]
// ---------------------------------------------------------------------------
__global__ void norm_k(float* __restrict__ C, const float* __restrict__ rs, int N) {
  const int row = blockIdx.y;
  const float inv = 1.0f / rs[row];
  const size_t rb = (size_t)row * N;
  const int c0 = blockIdx.x * 1024 + threadIdx.x;
#pragma unroll
  for (int j = 0; j < 4; ++j) {
    const int c = c0 + j * 256;
    if (c < N) C[rb + c] *= inv;
  }
}

// ---------------------------------------------------------------------------
extern "C" void kernel_launch(void* const* d_in, const int* in_sizes, int n_in,
                              void* d_out, int out_size, void* d_ws, size_t ws_size,
                              hipStream_t stream) {
  const float* x    = (const float*)d_in[0];
  const float* Wx1  = (const float*)d_in[1];
  const float* Wh1  = (const float*)d_in[2];
  const float* b1   = (const float*)d_in[3];
  const float* Wx2  = (const float*)d_in[4];
  const float* Wh2  = (const float*)d_in[5];
  const float* b2   = (const float*)d_in[6];
  const float* Wout = (const float*)d_in[7];
  const float* bout = (const float*)d_in[8];
  float* out = (float*)d_out;

  char* ws = (char*)d_ws;
  size_t off = 0;
  auto alloc = [&](size_t bytes) -> void* {
    off = (off + 255) & ~(size_t)255;
    void* p = ws + off;
    off += bytes;
    return p;
  };
  _Float16* A1h = (_Float16*)alloc((size_t)MROWS * 1536 * 2);   // 12.6 MB
  _Float16* B1t = (_Float16*)alloc((size_t)1024 * 1536 * 2);    // 3.1 MB
  float*    Xp1 = (float*)alloc((size_t)MROWS * 1024 * 4);      // 16.8 MB
  float*    H1  = (float*)alloc((size_t)TSTEPS * 8192 * 4);     // 16.8 MB
  float*    H2s = (float*)alloc((size_t)TSTEPS * 8192 * 4);     // 16.8 MB
  _Float16* H2f = (_Float16*)alloc((size_t)MROWS * 1024 * 2);   // 8.4 MB
  _Float16* BtO = (_Float16*)alloc((size_t)VPAD * 1024 * 2);    // 103 MB
  float*    rsums = (float*)alloc((size_t)MROWS * 4);
  unsigned* cnt = (unsigned*)alloc((size_t)2 * TSTEPS * 4 * sizeof(unsigned)); // 16KB
  unsigned* cnt1 = cnt;                 // c1[TSTEPS][4]
  unsigned* cnt2 = cnt + TSTEPS * 4;    // c2[TSTEPS][4]
  // total ~178 MB of d_ws

  hipMemsetAsync(cnt, 0, (size_t)2 * TSTEPS * 4 * sizeof(unsigned), stream);
  hipMemsetAsync(rsums, 0, (size_t)MROWS * 4, stream);

  // 1) converts
  a1cvt_k<<<(MROWS * DDIM) / 256, 256, 0, stream>>>(x, A1h);
  transcvt_k<<<dim3(16, 16), 256, 0, stream>>>(Wx1, B1t, 1024, 1536, 0, 0);     // hi
  transcvt_k<<<dim3(16, 16), 256, 0, stream>>>(Wx1, B1t, 1024, 1536, 512, 1);   // lo
  transcvt_k<<<dim3(16, 16), 256, 0, stream>>>(Wx1, B1t, 1024, 1536, 1024, 0);  // hi
  transcvt_k<<<dim3(VPAD / 64, 32), 256, 0, stream>>>(Wout, BtO, VOUT, 1024, 0, 0);

  // 2) Xp1 = [Xh|Xh|Xl] @ [W1h;W1l;W1h] + b1   (fp32-quality via split-fp16)
  gemm_f16_k<0><<<(1024 / 128) * 32, 256, 0, stream>>>(A1h, B1t, b1, Xp1, nullptr,
                                                       1536, 1024, 1024);

  // 3) cooperative recurrence (producer-consumer flags, no grid barrier)
  const size_t smem_bytes = (size_t)(16384 + 8192 + 8192 + 128) * 4;  // 131584
  hipFuncSetAttribute((const void*)rnn_coop_k,
                      hipFuncAttributeMaxDynamicSharedMemorySize, (int)smem_bytes);
  {
    const float* a0 = Xp1; const float* a1 = Wh1; const float* a2 = Wx2;
    const float* a3 = Wh2; const float* a4 = b2;
    float* a5 = H1; float* a6 = H2s; _Float16* a7 = H2f;
    unsigned* a8 = cnt1; unsigned* a9 = cnt2;
    void* kargs[] = {&a0, &a1, &a2, &a3, &a4, &a5, &a6, &a7, &a8, &a9};
    hipError_t ce = hipLaunchCooperativeKernel((const void*)rnn_coop_k,
                                               dim3(COOP_WGS), dim3(256), kargs,
                                               (unsigned)smem_bytes, stream);
    if (ce != hipSuccess) {
      (void)hipGetLastError();
      // 192 WGs @ 132KB LDS -> 1 WG/CU, 192 < 256 CUs: co-resident in practice
      rnn_coop_k<<<COOP_WGS, 256, smem_bytes, stream>>>(Xp1, Wh1, Wx2, Wh2, b2,
                                                        H1, H2s, H2f, cnt1, cnt2);
    }
  }

  // 4) head GEMM: out = exp(H2 @ Wout^T + bout), rowsums accumulated
  gemm_f16_k<1><<<(VPAD / 128) * 32, 256, 0, stream>>>(H2f, BtO, bout, out, rsums,
                                                       1024, VOUT, VOUT);

  // 5) normalize
  norm_k<<<dim3(50, MROWS), 256, 0, stream>>>(out, rsums, VOUT);
}

// Round 4
// 7352.919 us; speedup vs baseline: 2.2085x; 1.1133x over previous
//
#include <hip/hip_runtime.h>

// Problem constants
#define TSTEPS 512
#define NBATCH 8
#define DDIM   512
#define UDIM   1024
#define VOUT   50257
#define VPAD   50304      // 393 * 128
#define MROWS  4096       // B*T
#define COOP_WGS 192

typedef _Float16 half8 __attribute__((ext_vector_type(8)));
typedef float    floatx4 __attribute__((ext_vector_type(4)));
typedef unsigned uintx2  __attribute__((ext_vector_type(2)));
typedef unsigned uintx4  __attribute__((ext_vector_type(4)));

__device__ __forceinline__ void gl2lds16(const void* g, void* l) {
  __builtin_amdgcn_global_load_lds(
      (const __attribute__((address_space(1))) unsigned int*)g,
      (__attribute__((address_space(3))) unsigned int*)l, 16, 0, 0);
}

// --- LLC-coherent (cross-XCD) memory helpers: sc0 sc1 bypasses L1+L2 ---------
__device__ __forceinline__ floatx4 llc_load_f4(const float* p) {
  floatx4 r;
  asm volatile("global_load_dwordx4 %0, %1, off sc0 sc1" : "=v"(r) : "v"(p));
  return r;
}
__device__ __forceinline__ void llc_store_f4(float* p, floatx4 v) {
  asm volatile("global_store_dwordx4 %0, %1, off sc0 sc1" :: "v"(p), "v"(v) : "memory");
}
__device__ __forceinline__ void llc_store_f1(float* p, float v) {
  asm volatile("global_store_dword %0, %1, off sc0 sc1" :: "v"(p), "v"(v) : "memory");
}
__device__ __forceinline__ void llc_store_u1(unsigned* p, unsigned v) {
  asm volatile("global_store_dword %0, %1, off sc0 sc1" :: "v"(p), "v"(v) : "memory");
}
__device__ __forceinline__ unsigned llc_load_u1(const unsigned* p) {
  unsigned r;
  asm volatile("global_load_dword %0, %1, off sc0 sc1\n\ts_waitcnt vmcnt(0)"
               : "=v"(r) : "v"(p) : "memory");
  return r;
}
__device__ __forceinline__ uintx2 llc_load_u2(const unsigned* p) {
  uintx2 r;
  asm volatile("global_load_dwordx2 %0, %1, off sc0 sc1\n\ts_waitcnt vmcnt(0)"
               : "=v"(r) : "v"(p) : "memory");
  return r;
}
__device__ __forceinline__ void vm0_fence() {
  asm volatile("s_waitcnt vmcnt(0)" ::: "memory");
  __builtin_amdgcn_sched_barrier(0);
}

// ---------------------------------------------------------------------------
// Convert x[4096,512] fp32 -> A1' = [Xh | Xh | Xl]  [4096,1536] fp16
// ---------------------------------------------------------------------------
__global__ void a1cvt_k(const float* __restrict__ x, _Float16* __restrict__ A1) {
  const int idx = blockIdx.x * 256 + threadIdx.x;   // < 4096*512
  const int m = idx >> 9, k = idx & 511;
  const float v = x[idx];
  const _Float16 h = (_Float16)v;
  const _Float16 l = (_Float16)(v - (float)h);
  const size_t base = (size_t)m * 1536;
  A1[base + k]        = h;
  A1[base + 512 + k]  = h;
  A1[base + 1024 + k] = l;
}

// ---------------------------------------------------------------------------
// Transpose+convert: src[K][Nsrc] fp32 -> dst[n][kofs + k] fp16 (hi or lo part)
// grid = (dst_rows/64, Ksrc/32). Rows n >= Nsrc get zeros (pads B for GEMM).
// ---------------------------------------------------------------------------
__global__ void transcvt_k(const float* __restrict__ src, _Float16* __restrict__ dst,
                           int Nsrc, int LDK, int kofs, int mode) {
  __shared__ _Float16 tl[32][72];
  const int n0 = blockIdx.x * 64, k0 = blockIdx.y * 32;
  const int tid = threadIdx.x;
  {
    const int n = tid & 63, kq = tid >> 6;   // kq 0..3
#pragma unroll
    for (int j = 0; j < 8; ++j) {
      const int k = kq * 8 + j;
      const float v = (n0 + n < Nsrc) ? src[(size_t)(k0 + k) * Nsrc + n0 + n] : 0.f;
      const _Float16 h = (_Float16)v;
      tl[k][n] = mode ? (_Float16)(v - (float)h) : h;
    }
  }
  __syncthreads();
  {
    const int nn = tid >> 2, kc = tid & 3;   // nn 0..63
    half8 pk;
#pragma unroll
    for (int j = 0; j < 8; ++j) pk[j] = tl[kc * 8 + j][nn];
    *(half8*)(dst + (size_t)(n0 + nn) * LDK + kofs + k0 + kc * 8) = pk;
  }
}

// ---------------------------------------------------------------------------
// fp16 MFMA GEMM: C[M,N] = A[M,K] * B[N,K]^T(+bias). 128x128 tile, BK=64.
// grid.x = (N/128)*32, decode mt = bx&31 (M=4096 always), nt = bx>>5.
// EPI=0: C = acc + bias (fp32).  EPI=1: C = exp(acc+bias), rowsums += partials.
// LDS: XOR-swizzled 16B chunks: slot(r,cs) holds global chunk cs^(r&7).
// ---------------------------------------------------------------------------
template <int EPI>
__global__ __launch_bounds__(256, 3)
void gemm_f16_k(const _Float16* __restrict__ A, const _Float16* __restrict__ B,
                const float* __restrict__ bias, float* __restrict__ C,
                float* __restrict__ rowsums, int K, int Nvalid, int ldc) {
  __shared__ _Float16 sA[128 * 64];
  __shared__ _Float16 sB[128 * 64];
  __shared__ float rsl[128];
  const int bx = blockIdx.x;
  const int mt = bx & 31, nt = bx >> 5;
  const int m0 = mt << 7, n0 = nt << 7;
  const int tid = threadIdx.x;
  const int lane = tid & 63;
  const int wv = __builtin_amdgcn_readfirstlane(tid >> 6);
  const int wm = wv & 1, wn = wv >> 1;

  floatx4 acc[4][4];
#pragma unroll
  for (int i = 0; i < 4; ++i)
#pragma unroll
    for (int j = 0; j < 4; ++j)
#pragma unroll
      for (int r = 0; r < 4; ++r) acc[i][j][r] = 0.f;

  const int kiters = K >> 6;
  for (int kk = 0; kk < kiters; ++kk) {
    const int k0 = kk << 6;
#pragma unroll
    for (int i = 0; i < 4; ++i) {
      const int s = (wv << 8) + (i << 6) + lane;
      const int r = s >> 3;
      const int cg = (s & 7) ^ (r & 7);
      gl2lds16(A + (size_t)(m0 + r) * K + (k0 + (cg << 3)),
               sA + (size_t)((wv << 8) + (i << 6)) * 8);
      gl2lds16(B + (size_t)(n0 + r) * K + (k0 + (cg << 3)),
               sB + (size_t)((wv << 8) + (i << 6)) * 8);
    }
    __syncthreads();
    const int q = lane >> 4, li = lane & 15;
#pragma unroll
    for (int s2 = 0; s2 < 2; ++s2) {
      half8 af[4], bf[4];
#pragma unroll
      for (int mi = 0; mi < 4; ++mi) {
        const int r = (wm << 6) + (mi << 4) + li;
        const int cg = (s2 << 2) + q;
        af[mi] = *(const half8*)(sA + (size_t)((r << 3) + (cg ^ (r & 7))) * 8);
      }
#pragma unroll
      for (int ni = 0; ni < 4; ++ni) {
        const int r = (wn << 6) + (ni << 4) + li;
        const int cg = (s2 << 2) + q;
        bf[ni] = *(const half8*)(sB + (size_t)((r << 3) + (cg ^ (r & 7))) * 8);
      }
#pragma unroll
      for (int mi = 0; mi < 4; ++mi)
#pragma unroll
        for (int ni = 0; ni < 4; ++ni)
          acc[mi][ni] = __builtin_amdgcn_mfma_f32_16x16x32_f16(af[mi], bf[ni], acc[mi][ni], 0, 0, 0);
    }
    __syncthreads();
  }

  if (EPI == 1 && tid < 128) rsl[tid] = 0.f;
  __syncthreads();

  const int q = lane >> 4, li = lane & 15;
#pragma unroll
  for (int ni = 0; ni < 4; ++ni) {
    const int n = n0 + (wn << 6) + (ni << 4) + li;
    const bool nv = (n < Nvalid);
    const float bv = nv ? bias[n] : 0.f;
#pragma unroll
    for (int mi = 0; mi < 4; ++mi) {
      const int mb = m0 + (wm << 6) + (mi << 4) + (q << 2);
      float vr[4];
#pragma unroll
      for (int r = 0; r < 4; ++r) {
        float v = acc[mi][ni][r] + bv;
        if (EPI == 1) v = __expf(v);
        if (nv) C[(size_t)(mb + r) * ldc + n] = v;
        vr[r] = nv ? v : 0.f;
      }
      if (EPI == 1) {
#pragma unroll
        for (int r = 0; r < 4; ++r) {
          vr[r] += __shfl_xor(vr[r], 1, 64);
          vr[r] += __shfl_xor(vr[r], 2, 64);
          vr[r] += __shfl_xor(vr[r], 4, 64);
          vr[r] += __shfl_xor(vr[r], 8, 64);
        }
        if (li == 0) {
          const int lrow = (wm << 6) + (mi << 4) + (q << 2);
#pragma unroll
          for (int r = 0; r < 4; ++r) atomicAdd(&rsl[lrow + r], vr[r]);
        }
      }
    }
  }
  if (EPI == 1) {
    __syncthreads();
    if (tid < 128) atomicAdd(&rowsums[m0 + tid], rsl[tid]);
  }
}

// ---------------------------------------------------------------------------
// Cooperative recurrence kernel, per-WG flag stores (no RMW, no grid barrier).
// WG 0..63  : layer1, 16 cols each:  h1[t] = tanh(Xp1[t] + h1[t-1]@Wh1)
//             waits on f1[t-1][0..63] all set (wave-parallel poll, one LLC
//             round trip per iteration) -> the serial critical chain.
// WG 64..191: layer2, 8 cols each:   h2[t] = tanh(h1[t]@Wx2 + h2[t-1]@Wh2 + b2)
//             waits on f1[t][*] and f2[t-1][0..127]; trails with slack.
// Flags: f1[t][wg] (256B/step), f2[t][wg] (512B/step) — written once each
// (monotonic, no ABA), plain sc0sc1 stores (no RMW serialization). Per-step
// regions are line-disjoint: L1 polls step t-1, L2 polls step t, producers
// store step t flags -> no cross-group line contention.
// All cross-WG state moves via sc0 sc1 (LLC-coherent); no cache-wide fences.
// Thread map: tid = bg(1) | cg(2) | kg(5). k interleaved (k = kg*2 + 64j + {0,1}).
// Dynamic LDS: Wl[16*1024] | hbufA[8192] | hbufB[8192] | pbuf[128] floats.
// ---------------------------------------------------------------------------
__global__ __launch_bounds__(256)
void rnn_coop_k(const float* __restrict__ Xp1, const float* __restrict__ Wh1,
                const float* __restrict__ Wx2, const float* __restrict__ Wh2,
                const float* __restrict__ b2,
                float* __restrict__ H1, float* __restrict__ H2s,
                _Float16* __restrict__ H2f,
                unsigned* __restrict__ f1, unsigned* __restrict__ f2) {
  extern __shared__ float smem[];
  float* Wl    = smem;            // 16384 floats (64KB)
  float* hbufA = smem + 16384;    // 8192 floats (32KB)
  float* hbufB = smem + 24576;    // 8192 floats (32KB)
  float* pbuf  = smem + 32768;    // 128 floats

  const int wg = blockIdx.x;
  const bool isL1 = (wg < 64);
  const int tid = threadIdx.x;

  // Load weight slices into LDS (once, plain cached loads).
  if (isL1) {
    const int n0 = wg << 4;
    for (int idx = tid; idx < 16 * 1024; idx += 256) {
      const int k = idx >> 4, c = idx & 15;
      Wl[c * 1024 + k] = Wh1[(size_t)k * 1024 + n0 + c];
    }
  } else {
    const int n0 = (wg - 64) << 3;
    for (int idx = tid; idx < 8 * 1024; idx += 256) {
      const int k = idx >> 3, c = idx & 7;
      Wl[c * 1024 + k]       = Wx2[(size_t)k * 1024 + n0 + c];
      Wl[(8 + c) * 1024 + k] = Wh2[(size_t)k * 1024 + n0 + c];
    }
  }

  const int kg = tid & 31, cg = (tid >> 5) & 3, bg = tid >> 7;

  if (isL1) {
    // ---------------- layer 1: the serial critical chain ----------------
    const int n0c = (wg << 4) + (cg << 2);
    for (int t = 0; t < TSTEPS; ++t) {
      if (t > 0 && tid < 64) {
        const unsigned* fp = f1 + ((t - 1) << 6) + tid;
        while (!__all(llc_load_u1(fp) != 0)) __builtin_amdgcn_s_sleep(1);
      }
      __syncthreads();  // flag observed by wave0 releases all; covers Wl at t=0

      if (t > 0) {
        const float* src = H1 + (size_t)(t - 1) * 8192;
        floatx4 tmp[8];
#pragma unroll
        for (int i = 0; i < 8; ++i) tmp[i] = llc_load_f4(src + ((tid + (i << 8)) << 2));
        vm0_fence();
#pragma unroll
        for (int i = 0; i < 8; ++i) ((floatx4*)hbufA)[tid + (i << 8)] = tmp[i];
      } else {
        const floatx4 z = {0.f, 0.f, 0.f, 0.f};
#pragma unroll
        for (int i = 0; i < 8; ++i) ((floatx4*)hbufA)[tid + (i << 8)] = z;
      }
      __syncthreads();

      float av[4][4];
#pragma unroll
      for (int b = 0; b < 4; ++b)
#pragma unroll
        for (int i = 0; i < 4; ++i) av[b][i] = 0.f;
#pragma unroll 4
      for (int j = 0; j < 16; ++j) {
        const int k0 = (kg << 1) + (j << 6);
        float2 hv[4], wvec[4];
#pragma unroll
        for (int b = 0; b < 4; ++b)
          hv[b] = *(const float2*)(hbufA + ((bg << 2) + b) * 1024 + k0);
#pragma unroll
        for (int i = 0; i < 4; ++i)
          wvec[i] = *(const float2*)(Wl + ((cg << 2) + i) * 1024 + k0);
#pragma unroll
        for (int b = 0; b < 4; ++b)
#pragma unroll
          for (int i = 0; i < 4; ++i)
            av[b][i] += hv[b].x * wvec[i].x + hv[b].y * wvec[i].y;
      }
#pragma unroll
      for (int b = 0; b < 4; ++b)
#pragma unroll
        for (int i = 0; i < 4; ++i) {
          float v = av[b][i];
          v += __shfl_xor(v, 1, 64);
          v += __shfl_xor(v, 2, 64);
          v += __shfl_xor(v, 4, 64);
          v += __shfl_xor(v, 8, 64);
          v += __shfl_xor(v, 16, 64);
          av[b][i] = v;
        }
      if (kg == 0) {
#pragma unroll
        for (int b = 0; b < 4; ++b) {
          const int bb = (bg << 2) + b;
          const float4 x4 = *(const float4*)(Xp1 + ((size_t)bb * TSTEPS + t) * 1024 + n0c);
          floatx4 h4;
          h4.x = tanhf(av[b][0] + x4.x);
          h4.y = tanhf(av[b][1] + x4.y);
          h4.z = tanhf(av[b][2] + x4.z);
          h4.w = tanhf(av[b][3] + x4.w);
          llc_store_f4(H1 + (size_t)t * 8192 + (size_t)bb * 1024 + n0c, h4);
        }
      }
      vm0_fence();      // this thread's sc1 stores acked at LLC
      __syncthreads();  // all threads' stores acked
      if (tid == 0) llc_store_u1(f1 + (t << 6) + wg, 1u);
    }
  } else {
    // ---------------- layer 2: trails layer 1 by one step ----------------
    const int n0 = (wg - 64) << 3;
    const float* hA_sel = (cg >= 2) ? hbufB : hbufA;
    for (int t = 0; t < TSTEPS; ++t) {
      if (tid < 64) {
        for (;;) {
          const unsigned a = llc_load_u1(f1 + (t << 6) + tid);
          unsigned b0 = 1u, b1 = 1u;
          if (t > 0) {
            const uintx2 b = llc_load_u2(f2 + ((t - 1) << 7) + (tid << 1));
            b0 = b.x; b1 = b.y;
          }
          if (__all((a != 0u) & (b0 != 0u) & (b1 != 0u))) break;
          __builtin_amdgcn_s_sleep(8);  // slack: trails L1 by a step
        }
      }
      __syncthreads();

      {
        const float* srcA = H1 + (size_t)t * 8192;
        floatx4 ta[8];
#pragma unroll
        for (int i = 0; i < 8; ++i) ta[i] = llc_load_f4(srcA + ((tid + (i << 8)) << 2));
        if (t > 0) {
          const float* srcB = H2s + (size_t)(t - 1) * 8192;
          floatx4 tb[8];
#pragma unroll
          for (int i = 0; i < 8; ++i) tb[i] = llc_load_f4(srcB + ((tid + (i << 8)) << 2));
          vm0_fence();
#pragma unroll
          for (int i = 0; i < 8; ++i) ((floatx4*)hbufA)[tid + (i << 8)] = ta[i];
#pragma unroll
          for (int i = 0; i < 8; ++i) ((floatx4*)hbufB)[tid + (i << 8)] = tb[i];
        } else {
          vm0_fence();
          const floatx4 z = {0.f, 0.f, 0.f, 0.f};
#pragma unroll
          for (int i = 0; i < 8; ++i) {
            ((floatx4*)hbufA)[tid + (i << 8)] = ta[i];
            ((floatx4*)hbufB)[tid + (i << 8)] = z;
          }
        }
      }
      __syncthreads();

      float av[4][4];
#pragma unroll
      for (int b = 0; b < 4; ++b)
#pragma unroll
        for (int i = 0; i < 4; ++i) av[b][i] = 0.f;
#pragma unroll 4
      for (int j = 0; j < 16; ++j) {
        const int k0 = (kg << 1) + (j << 6);
        float2 hv[4], wvec[4];
#pragma unroll
        for (int b = 0; b < 4; ++b)
          hv[b] = *(const float2*)(hA_sel + ((bg << 2) + b) * 1024 + k0);
#pragma unroll
        for (int i = 0; i < 4; ++i)
          wvec[i] = *(const float2*)(Wl + ((cg << 2) + i) * 1024 + k0);
#pragma unroll
        for (int b = 0; b < 4; ++b)
#pragma unroll
          for (int i = 0; i < 4; ++i)
            av[b][i] += hv[b].x * wvec[i].x + hv[b].y * wvec[i].y;
      }
#pragma unroll
      for (int b = 0; b < 4; ++b)
#pragma unroll
        for (int i = 0; i < 4; ++i) {
          float v = av[b][i];
          v += __shfl_xor(v, 1, 64);
          v += __shfl_xor(v, 2, 64);
          v += __shfl_xor(v, 4, 64);
          v += __shfl_xor(v, 8, 64);
          v += __shfl_xor(v, 16, 64);
          av[b][i] = v;
        }
      if (kg == 0) {
#pragma unroll
        for (int b = 0; b < 4; ++b)
#pragma unroll
          for (int i = 0; i < 4; ++i)
            pbuf[((cg << 2) + i) * 8 + (bg << 2) + b] = av[b][i];
      }
      __syncthreads();
      if (tid < 64) {
        const int c = tid & 7, b = tid >> 3;
        const int n = n0 + c;
        const float pre = pbuf[c * 8 + b] + pbuf[(c + 8) * 8 + b] + b2[n];
        const float h = tanhf(pre);
        llc_store_f1(H2s + (size_t)t * 8192 + (size_t)b * 1024 + n, h);
        H2f[((size_t)b * TSTEPS + t) * 1024 + n] = (_Float16)h;  // plain: post-kernel use
      }
      vm0_fence();
      __syncthreads();
      if (tid == 0) llc_store_u1(f2 + (t << 7) + (wg - 64), 1u);
    }
  }
}

// ---------------------------------------------------------------------------
// out[row, :] *= 1/rowsum[row]
// ---------------------------------------------------------------------------
__global__ void norm_k(float* __restrict__ C, const float* __restrict__ rs, int N) {
  const int row = blockIdx.y;
  const float inv = 1.0f / rs[row];
  const size_t rb = (size_t)row * N;
  const int c0 = blockIdx.x * 1024 + threadIdx.x;
#pragma unroll
  for (int j = 0; j < 4; ++j) {
    const int c = c0 + j * 256;
    if (c < N) C[rb + c] *= inv;
  }
}

// ---------------------------------------------------------------------------
extern "C" void kernel_launch(void* const* d_in, const int* in_sizes, int n_in,
                              void* d_out, int out_size, void* d_ws, size_t ws_size,
                              hipStream_t stream) {
  const float* x    = (const float*)d_in[0];
  const float* Wx1  = (const float*)d_in[1];
  const float* Wh1  = (const float*)d_in[2];
  const float* b1   = (const float*)d_in[3];
  const float* Wx2  = (const float*)d_in[4];
  const float* Wh2  = (const float*)d_in[5];
  const float* b2   = (const float*)d_in[6];
  const float* Wout = (const float*)d_in[7];
  const float* bout = (const float*)d_in[8];
  float* out = (float*)d_out;

  char* ws = (char*)d_ws;
  size_t off = 0;
  auto alloc = [&](size_t bytes) -> void* {
    off = (off + 255) & ~(size_t)255;
    void* p = ws + off;
    off += bytes;
    return p;
  };
  _Float16* A1h = (_Float16*)alloc((size_t)MROWS * 1536 * 2);   // 12.6 MB
  _Float16* B1t = (_Float16*)alloc((size_t)1024 * 1536 * 2);    // 3.1 MB
  float*    Xp1 = (float*)alloc((size_t)MROWS * 1024 * 4);      // 16.8 MB
  float*    H1  = (float*)alloc((size_t)TSTEPS * 8192 * 4);     // 16.8 MB
  float*    H2s = (float*)alloc((size_t)TSTEPS * 8192 * 4);     // 16.8 MB
  _Float16* H2f = (_Float16*)alloc((size_t)MROWS * 1024 * 2);   // 8.4 MB
  _Float16* BtO = (_Float16*)alloc((size_t)VPAD * 1024 * 2);    // 103 MB
  float*    rsums = (float*)alloc((size_t)MROWS * 4);
  unsigned* flg1 = (unsigned*)alloc((size_t)TSTEPS * 64 * sizeof(unsigned));   // 128KB
  unsigned* flg2 = (unsigned*)alloc((size_t)TSTEPS * 128 * sizeof(unsigned));  // 256KB
  // total ~178 MB of d_ws

  hipMemsetAsync(flg1, 0, (size_t)TSTEPS * 64 * sizeof(unsigned), stream);
  hipMemsetAsync(flg2, 0, (size_t)TSTEPS * 128 * sizeof(unsigned), stream);
  hipMemsetAsync(rsums, 0, (size_t)MROWS * 4, stream);

  // 1) converts
  a1cvt_k<<<(MROWS * DDIM) / 256, 256, 0, stream>>>(x, A1h);
  transcvt_k<<<dim3(16, 16), 256, 0, stream>>>(Wx1, B1t, 1024, 1536, 0, 0);     // hi
  transcvt_k<<<dim3(16, 16), 256, 0, stream>>>(Wx1, B1t, 1024, 1536, 512, 1);   // lo
  transcvt_k<<<dim3(16, 16), 256, 0, stream>>>(Wx1, B1t, 1024, 1536, 1024, 0);  // hi
  transcvt_k<<<dim3(VPAD / 64, 32), 256, 0, stream>>>(Wout, BtO, VOUT, 1024, 0, 0);

  // 2) Xp1 = [Xh|Xh|Xl] @ [W1h;W1l;W1h] + b1   (fp32-quality via split-fp16)
  gemm_f16_k<0><<<(1024 / 128) * 32, 256, 0, stream>>>(A1h, B1t, b1, Xp1, nullptr,
                                                       1536, 1024, 1024);

  // 3) cooperative recurrence (producer-consumer flags, no grid barrier)
  const size_t smem_bytes = (size_t)(16384 + 8192 + 8192 + 128) * 4;  // 131584
  hipFuncSetAttribute((const void*)rnn_coop_k,
                      hipFuncAttributeMaxDynamicSharedMemorySize, (int)smem_bytes);
  {
    const float* a0 = Xp1; const float* a1 = Wh1; const float* a2 = Wx2;
    const float* a3 = Wh2; const float* a4 = b2;
    float* a5 = H1; float* a6 = H2s; _Float16* a7 = H2f;
    unsigned* a8 = flg1; unsigned* a9 = flg2;
    void* kargs[] = {&a0, &a1, &a2, &a3, &a4, &a5, &a6, &a7, &a8, &a9};
    hipError_t ce = hipLaunchCooperativeKernel((const void*)rnn_coop_k,
                                               dim3(COOP_WGS), dim3(256), kargs,
                                               (unsigned)smem_bytes, stream);
    if (ce != hipSuccess) {
      (void)hipGetLastError();
      // 192 WGs @ 132KB LDS -> 1 WG/CU, 192 < 256 CUs: co-resident in practice
      rnn_coop_k<<<COOP_WGS, 256, smem_bytes, stream>>>(Xp1, Wh1, Wx2, Wh2, b2,
                                                        H1, H2s, H2f, flg1, flg2);
    }
  }

  // 4) head GEMM: out = exp(H2 @ Wout^T + bout), rowsums accumulated
  gemm_f16_k<1><<<(VPAD / 128) * 32, 256, 0, stream>>>(H2f, BtO, bout, out, rsums,
                                                       1024, VOUT, VOUT);

  // 5) normalize
  norm_k<<<dim3(50, MROWS), 256, 0, stream>>>(out, rsums, VOUT);
}